// Round 7
// baseline (286.054 us; speedup 1.0000x reference)
//
#include <hip/hip_runtime.h>

#define B_ 8
#define C_ 128
#define WH_ 2304
#define N_ 8192

typedef unsigned short u16;
typedef float f32x4 __attribute__((ext_vector_type(4)));
typedef short s16x8 __attribute__((ext_vector_type(8)));
typedef short s16x4 __attribute__((ext_vector_type(4)));
typedef unsigned int u32x2 __attribute__((ext_vector_type(2)));

typedef const unsigned int __attribute__((address_space(1))) ga_u32;
typedef unsigned int __attribute__((address_space(3))) lds_u32;

#define LOG2E 1.4426950408889634f
#define MOFF  64.0f   // fixed softmax offset in log2 domain (no running max)

__device__ __forceinline__ float bf2f(u16 u){
    union { unsigned int i; float f; } x; x.i = ((unsigned int)u) << 16; return x.f;
}
__device__ __forceinline__ u16 f2bf(float f){
    union { float f; unsigned int i; } x; x.f = f;
    unsigned int r = x.i + 0x7fffu + ((x.i >> 16) & 1u);
    return (u16)(r >> 16);
}
// packed f32x2 -> bf16x2 (RNE), single VALU op
__device__ __forceinline__ unsigned int cvtpk(float a, float b){
    unsigned int r;
    asm("v_cvt_pk_bf16_f32 %0, %1, %2" : "=v"(r) : "v"(a), "v"(b));
    return r;
}
// element index inside a [rows][128] bf16 LDS tile with 16B-block xor swizzle
__device__ __forceinline__ int swz(int row, int col){
    return row*128 + ((((col >> 3) ^ (row & 15)) << 3) | (col & 7));
}
__device__ __forceinline__ f32x4 fzero(){ f32x4 z = {0.f, 0.f, 0.f, 0.f}; return z; }
__device__ __forceinline__ f32x4 fmoff(){ f32x4 z = {-MOFF, -MOFF, -MOFF, -MOFF}; return z; }
__device__ __forceinline__ f32x4 mfma16(s16x8 a, s16x8 b, f32x4 c){
    return __builtin_amdgcn_mfma_f32_16x16x32_bf16(a, b, c, 0, 0, 0);
}
__device__ __forceinline__ void gld16(const void* g, void* l){
    __builtin_amdgcn_global_load_lds((ga_u32*)g, (lds_u32*)l, 16, 0, 0);
}
__device__ __forceinline__ s16x8 ldsf(const u16* p){ return *(const s16x8*)p; }
__device__ __forceinline__ s16x8 cvt8(const float* p){
    s16x8 r;
    #pragma unroll
    for (int j = 0; j < 8; j++) r[j] = (short)f2bf(p[j]);
    return r;
}

// ---------------- K0: weights -> bf16 transposed [out][in] ----------------
__global__ __launch_bounds__(256) void k_prep(
    const float* __restrict__ Wq, const float* __restrict__ Wk,
    const float* __restrict__ Wv, const float* __restrict__ Wo,
    const float* __restrict__ Wg, u16* __restrict__ Wt)
{
    const int gid = blockIdx.x*256 + threadIdx.x;     // 5*16384
    const int mi = gid >> 14, e = gid & 16383;
    const int o = e >> 7, i = e & 127;
    const float* src = (mi==0)?Wq:(mi==1)?Wk:(mi==2)?Wv:(mi==3)?Wo:Wg;
    Wt[mi*16384 + o*128 + i] = f2bf(src[i*128 + o]);
}

// ---------------- K1a: pk/pv, 128-row tiles, 8 waves, 32 KB LDS -----------------
// Weights as B-fragments straight from global (L1-resident 32 KB/matrix).
// Af reused wave-privately for Ko staging (each wave owns rows w*16..w*16+15).
// V written directly to global as V^T from the accumulator (no staging).
__global__ __launch_bounds__(512, 4) void k_proj_kv(
    const float* __restrict__ feat1,
    const float* __restrict__ bk, const float* __restrict__ bv,
    const u16* __restrict__ Wt,
    u16* __restrict__ Kb, u16* __restrict__ Vb)
{
    __shared__ __attribute__((aligned(16))) u16 Af[128*128];   // 32 KB, swz
    const int t = threadIdx.x;
    const int b = blockIdx.x >> 6;
    const int n0 = (blockIdx.x & 63) * 128;
    for (int idx = t; idx < 128*32; idx += 512){       // f32x4 coalesced staging
        const int nl = (idx & 31) << 2, c = idx >> 5;
        const f32x4 v = *(const f32x4*)&feat1[((size_t)b*C_ + c)*N_ + n0 + nl];
        Af[swz(nl+0, c)] = f2bf(v[0]); Af[swz(nl+1, c)] = f2bf(v[1]);
        Af[swz(nl+2, c)] = f2bf(v[2]); Af[swz(nl+3, c)] = f2bf(v[3]);
    }
    __syncthreads();
    const int lane = t & 63, w = t >> 6, qq = lane >> 4, m = lane & 15;
    const int ar = w*16 + m;
    s16x8 aA[4];
    #pragma unroll
    for (int kt = 0; kt < 4; kt++)
        aA[kt] = ldsf(&Af[ar*128 + (((kt*4 + qq) ^ (ar & 15)) << 3)]);
    const u16* WkT = Wt + 16384;
    const u16* WvT = Wt + 32768;
    f32x4 acc[8];
    // ---- K GEMM ----
    #pragma unroll
    for (int ct = 0; ct < 8; ct++) acc[ct] = fzero();
    #pragma unroll
    for (int kt = 0; kt < 4; kt++){
        #pragma unroll
        for (int ct = 0; ct < 8; ct++){
            const s16x8 bf = *(const s16x8*)&WkT[(ct*16 + m)*128 + kt*32 + qq*8];
            acc[ct] = mfma16(aA[kt], bf, acc[ct]);
        }
    }
    // K epilogue: wave-private Ko rows (same rows this wave read for aA)
    u16* Ko = Af;
    #pragma unroll
    for (int ct = 0; ct < 8; ct++){
        const int col = ct*16 + m;
        const float bkv = bk[col];
        #pragma unroll
        for (int i = 0; i < 4; i++)
            Ko[swz(w*16 + qq*4 + i, col)] = f2bf(acc[ct][i] + bkv);
    }
    #pragma unroll
    for (int j = 0; j < 4; j++){       // wave-private readback, coalesced store
        const int chunk = j*64 + lane;
        const int row = w*16 + (chunk >> 4);
        const int cb = chunk & 15;
        s16x8 v = ldsf(&Ko[row*128 + ((cb ^ (row & 15)) << 3)]);
        *(s16x8*)&Kb[((size_t)b*N_ + n0 + row)*C_ + cb*8] = v;
    }
    // ---- V GEMM (reuse acc, aA) ----
    #pragma unroll
    for (int ct = 0; ct < 8; ct++) acc[ct] = fzero();
    #pragma unroll
    for (int kt = 0; kt < 4; kt++){
        #pragma unroll
        for (int ct = 0; ct < 8; ct++){
            const s16x8 bf = *(const s16x8*)&WvT[(ct*16 + m)*128 + kt*32 + qq*8];
            acc[ct] = mfma16(aA[kt], bf, acc[ct]);
        }
    }
    // direct V^T store: lane holds rows n = w*16 + qq*4 + 0..3 of channel col
    #pragma unroll
    for (int ct = 0; ct < 8; ct++){
        const int col = ct*16 + m;
        const float bvv = bv[col];
        u32x2 pk;
        pk.x = cvtpk(acc[ct][0] + bvv, acc[ct][1] + bvv);
        pk.y = cvtpk(acc[ct][2] + bvv, acc[ct][3] + bvv);
        *(u32x2*)&Vb[((size_t)b*C_ + col)*N_ + n0 + w*16 + qq*4] = pk;
    }
}

// ---------------- K1b: pq/geo + gate, 64-row tiles, 16 KB LDS -------------------
__global__ __launch_bounds__(256, 3) void k_proj_qg(
    const float* __restrict__ feat0, const float* __restrict__ geo,
    const float* __restrict__ bq, const float* __restrict__ bg,
    const float* __restrict__ Wgate, const float* __restrict__ bgate,
    const u16* __restrict__ Wt,
    u16* __restrict__ Qb, u16* __restrict__ Gb)
{
    __shared__ __attribute__((aligned(16))) u16 Aq[64*128];    // 16 KB, swz
    const int t = threadIdx.x;
    const int b = blockIdx.x / 36;
    const int r0 = (blockIdx.x % 36) * 64;
    for (int idx = t; idx < 64*32; idx += 256){        // f32x4 coalesced staging
        const int r = (idx & 15) << 2, c = idx >> 4;
        const f32x4 v = *(const f32x4*)&feat0[((size_t)b*C_ + c)*WH_ + r0 + r];
        Aq[swz(r+0, c)] = f2bf(v[0]); Aq[swz(r+1, c)] = f2bf(v[1]);
        Aq[swz(r+2, c)] = f2bf(v[2]); Aq[swz(r+3, c)] = f2bf(v[3]);
    }
    __syncthreads();
    const int lane = t & 63, w = t >> 6, qq = lane >> 4, m = lane & 15;
    const int ar = w*16 + m;
    s16x8 aQ[4], aG[4];
    #pragma unroll
    for (int kt = 0; kt < 4; kt++){
        aQ[kt] = ldsf(&Aq[ar*128 + (((kt*4 + qq) ^ (ar & 15)) << 3)]);
        aG[kt] = cvt8(&geo[((size_t)b*WH_ + r0 + ar)*C_ + kt*32 + qq*8]);
    }
    f32x4 accq[8], accg[8];
    #pragma unroll
    for (int ct = 0; ct < 8; ct++){ accq[ct] = fzero(); accg[ct] = fzero(); }
    #pragma unroll
    for (int kt = 0; kt < 4; kt++){
        #pragma unroll
        for (int ct = 0; ct < 8; ct++){
            const int bn = ct*16 + m;
            const s16x8 b1 = *(const s16x8*)&Wt[bn*128 + kt*32 + qq*8];
            const s16x8 b2 = *(const s16x8*)&Wt[65536 + bn*128 + kt*32 + qq*8];
            accq[ct] = mfma16(aQ[kt], b1, accq[ct]);
            accg[ct] = mfma16(aG[kt], b2, accg[ct]);
        }
    }
    // fold biases in place (frees the bias registers before the gate phase)
    #pragma unroll
    for (int ct = 0; ct < 8; ct++){
        const int col = ct*16 + m;
        const float bqv = bq[col], bgv = bg[col];
        #pragma unroll
        for (int i = 0; i < 4; i++){ accq[ct][i] += bqv; accg[ct][i] += bgv; }
    }
    float w1v[8], w2v[8];
    #pragma unroll
    for (int ct = 0; ct < 8; ct++){
        const int col = ct*16 + m;
        w1v[ct] = Wgate[col]; w2v[ct] = Wgate[C_ + col];
    }
    const float bg0 = bgate[0];
    float gate[4];
    #pragma unroll
    for (int i = 0; i < 4; i++){
        float p = 0.f;
        #pragma unroll
        for (int ct = 0; ct < 8; ct++)
            p += accq[ct][i] * w1v[ct] + accg[ct][i] * w2v[ct];
        #pragma unroll
        for (int off = 1; off < 16; off <<= 1) p += __shfl_xor(p, off, 64);
        gate[i] = 1.f / (1.f + __expf(-(p + bg0)));
    }
    // St reuses Aq wave-privately (rows w*16..w*16+15, the rows this wave read)
    u16* St = Aq;
    #pragma unroll
    for (int ct = 0; ct < 8; ct++){
        #pragma unroll
        for (int i = 0; i < 4; i++){
            const float pq = accq[ct][i] + gate[i] * accg[ct][i];
            St[swz(w*16 + qq*4 + i, ct*16 + m)] = f2bf(pq * LOG2E);
        }
    }
    #pragma unroll
    for (int j = 0; j < 4; j++){
        const int chunk = j*64 + lane;
        const int row = w*16 + (chunk >> 4);
        const int cb = chunk & 15;
        s16x8 v = ldsf(&St[row*128 + ((cb ^ (row & 15)) << 3)]);
        *(s16x8*)&Qb[((size_t)b*WH_ + r0 + row)*C_ + cb*8] = v;
    }
    #pragma unroll
    for (int ct = 0; ct < 8; ct++){
        #pragma unroll
        for (int i = 0; i < 4; i++)
            St[swz(w*16 + qq*4 + i, ct*16 + m)] = f2bf(accg[ct][i]);
    }
    #pragma unroll
    for (int j = 0; j < 4; j++){
        const int chunk = j*64 + lane;
        const int row = w*16 + (chunk >> 4);
        const int cb = chunk & 15;
        s16x8 v = ldsf(&St[row*128 + ((cb ^ (row & 15)) << 3)]);
        *(s16x8*)&Gb[((size_t)b*WH_ + r0 + row)*C_ + cb*8] = v;
    }
}

// ---------------- K2: flash attention (round-6 proven) --------------------------
__global__ __launch_bounds__(1024, 4) void k_flash(
    const u16* __restrict__ Qb, const u16* __restrict__ Kb, const u16* __restrict__ Vb,
    u16* __restrict__ Opart, float* __restrict__ Lp)
{
    __shared__ __attribute__((aligned(16))) u16 KP0[128*128];   // 32 KB each
    __shared__ __attribute__((aligned(16))) u16 KP1[128*128];
    __shared__ __attribute__((aligned(16))) u16 Vt0[128*128];
    __shared__ __attribute__((aligned(16))) u16 Vt1[128*128];
    const int t = threadIdx.x;
    const int lane = t & 63, w = t >> 6;            // 16 waves
    const int q = lane >> 4, m = lane & 15;         // q = quad
    const int b = blockIdx.x & 7;
    const int s = blockIdx.x >> 3;                  // slot 0..31

    f32x4 o[8];
    f32x4 l_acc;                                    // denominator via ones-MFMA
    s16x8 qf[4];
    s16x8 ones8;
    #pragma unroll
    for (int j = 0; j < 8; j++) ones8[j] = (short)0x3F80;   // bf16 1.0

    auto issue = [&](int k){
        const int u = s*18 + k;
        const int n0 = (u & 63) * 128;              // sequential chunk order
        u16* KPd = (k & 1) ? KP1 : KP0;
        u16* Vtd = (k & 1) ? Vt1 : Vt0;
        #pragma unroll
        for (int j = 0; j < 2; j++){
            const int r = w*8 + j*4 + q;            // LDS row 0..127
            // K global row permuted: pi(r) = [pair|q2|h|i] from r = [pair|h|q2|i]
            const int pr = (r & 96) | ((r & 12) << 1) | ((r & 16) >> 2) | (r & 3);
            gld16(Kb + ((size_t)b*N_ + n0 + pr)*C_ + ((m ^ (r & 15)) << 3), &KPd[(w*8 + j*4)*128]);
            gld16(Vb + ((size_t)b*C_ + r)*N_ + n0 + ((m ^ (r & 15)) << 3), &Vtd[(w*8 + j*4)*128]);
        }
    };
    auto load_q = [&](int qb){
        const size_t qrow0 = (size_t)b*WH_ + qb*256;
        #pragma unroll
        for (int kt = 0; kt < 4; kt++)
            qf[kt] = *(const s16x8*)&Qb[(qrow0 + w*16 + m)*C_ + kt*32 + q*8];
    };
    auto zero_acc = [&](){
        #pragma unroll
        for (int ct = 0; ct < 8; ct++) o[ct] = fzero();
        l_acc = fzero();
    };
    auto flush = [&](int qb){
        const int sf = (qb * 64) / 18;
        const size_t pbase = ((size_t)(b*9 + qb)*5 + (s - sf)) * 256;
        #pragma unroll
        for (int ct = 0; ct < 8; ct++){
            u32x2 pk;
            pk.x = cvtpk(o[ct][0], o[ct][1]);
            pk.y = cvtpk(o[ct][2], o[ct][3]);
            *(u32x2*)&Opart[(pbase + w*16 + m)*128 + ct*16 + q*4] = pk;
        }
        // l_acc[i] identical across i and q (ones-MFMA row sums); one lane set writes
        if (q == 0) Lp[pbase + w*16 + m] = l_acc[0];
    };

    issue(0);
    int cur_qb = (s*18) >> 6;
    load_q(cur_qb);
    zero_acc();

    for (int k = 0; k < 18; k++){
        __syncthreads();                 // drains prefetch(k) (a full compute-phase old) + buffer sync
        if (k < 17) issue(k + 1);        // overlaps with compute below
        const u16* KPc = (k & 1) ? KP1 : KP0;
        const u16* Vtc = (k & 1) ? Vt1 : Vt0;

        // Two half-phases: S^T (C-init = -MOFF) for 4 n-groups -> fused K32 PV.
        #pragma unroll
        for (int h = 0; h < 2; h++){
            s16x4 pexp[4];
            #pragma unroll
            for (int n2 = 0; n2 < 4; n2++){
                const int nt = h*4 + n2;
                f32x4 s0 = fmoff();
                const int bn = nt*16 + m;
                #pragma unroll
                for (int kt = 0; kt < 4; kt++){
                    s16x8 kf = ldsf(&KPc[bn*128 + (((kt*4 + q) ^ (bn & 15)) << 3)]);
                    s0 = mfma16(kf, qf[kt], s0);
                }
                union { u32x2 u; s16x4 v; } pp;
                pp.u.x = cvtpk(exp2f(s0[0]), exp2f(s0[1]));
                pp.u.y = cvtpk(exp2f(s0[2]), exp2f(s0[3]));
                pexp[n2] = pp.v;
            }
            // O^T += V^T·P^T as K=32: A = V^T 8-slice (natural order), B = pexp concat
            const s16x8 p80 = __builtin_shufflevector(pexp[0], pexp[1], 0,1,2,3,4,5,6,7);
            const s16x8 p81 = __builtin_shufflevector(pexp[2], pexp[3], 0,1,2,3,4,5,6,7);
            l_acc = mfma16(ones8, p80, l_acc);      // denominator: sum over 32 n per qrow
            l_acc = mfma16(ones8, p81, l_acc);
            #pragma unroll
            for (int ct = 0; ct < 8; ct++){
                const int cc = ct*16 + m;
                const int pair0 = h*2;
                s16x8 vf0 = ldsf(&Vtc[cc*128 + ((((pair0+0)*4 + q) ^ (cc & 15)) << 3)]);
                s16x8 vf1 = ldsf(&Vtc[cc*128 + ((((pair0+1)*4 + q) ^ (cc & 15)) << 3)]);
                o[ct] = mfma16(vf0, p80, o[ct]);
                o[ct] = mfma16(vf1, p81, o[ct]);
            }
        }
        // q-tile bookkeeping (flush uses registers + global stores only; no LDS hazard)
        const int nqb = (k < 17) ? ((s*18 + k + 1) >> 6) : -1;
        if (nqb != cur_qb){
            flush(cur_qb);
            if (nqb >= 0){ load_q(nqb); zero_acc(); cur_qb = nqb; }
        }
    }
}

// ---------------- K3: combine partials, @Wo+bo, geo-gate, +feat0, transpose --------
__global__ __launch_bounds__(256) void k_out(
    const u16* __restrict__ Opart, const float* __restrict__ Lp,
    const float* __restrict__ bo, const u16* __restrict__ Wt,
    const u16* __restrict__ Gb, const float* __restrict__ feat0,
    float* __restrict__ outp)
{
    __shared__ __attribute__((aligned(16))) u16 AO[128*128];   // 32 KB
    __shared__ u16 Tr[128*130];                                 // 33.3 KB
    const int t = threadIdx.x;
    const int bqt = blockIdx.x;                 // 0..143 (half q-tiles of 128 rows)
    const int qt2 = bqt >> 1, half = bqt & 1;
    const int b = qt2 / 9, qb = qt2 % 9;
    const int gr0 = qb*256 + half*128;          // row base within batch
    const u16* WoT = Wt + 49152;
    const float rsC = 0.088388347648318447f;    // 1/sqrt(128)
    const int sf = (qb*64) / 18;
    const int sl = (qb*64 + 63) / 18;
    const int cnt = sl - sf + 1;                // 4 or 5
    for (int idx = t; idx < 128*16; idx += 256){
        int r = idx >> 4, cb = idx & 15;
        float num[8];
        #pragma unroll
        for (int j = 0; j < 8; j++) num[j] = 0.f;
        float den = 0.f;
        for (int ss = 0; ss < cnt; ss++){
            const size_t base = ((size_t)qt2*5 + ss)*256 + half*128 + r;
            s16x8 v = *(const s16x8*)&Opart[base*128 + cb*8];
            #pragma unroll
            for (int j = 0; j < 8; j++) num[j] += bf2f((u16)v[j]);
            den += Lp[base];
        }
        const float sc = rsC / den;
        s16x8 o8;
        #pragma unroll
        for (int j = 0; j < 8; j++) o8[j] = (short)f2bf(num[j] * sc);
        *(s16x8*)&AO[r*128 + ((cb ^ (r & 15)) << 3)] = o8;
    }
    __syncthreads();
    const int lane = t & 63, w = t >> 6;
    const int q = lane >> 4, m = lane & 15;
    const int rw = w * 32;
    f32x4 acc[2][8];
    #pragma unroll
    for (int rt = 0; rt < 2; rt++){
        #pragma unroll
        for (int ct = 0; ct < 8; ct++) acc[rt][ct] = fzero();
    }
    #pragma unroll
    for (int kt = 0; kt < 4; kt++){
        s16x8 a0, a1;
        { const int ar = rw + m;      a0 = ldsf(&AO[ar*128 + (((kt*4 + q) ^ (ar & 15)) << 3)]); }
        { const int ar = rw + 16 + m; a1 = ldsf(&AO[ar*128 + (((kt*4 + q) ^ (ar & 15)) << 3)]); }
        #pragma unroll
        for (int ct = 0; ct < 8; ct++){
            const s16x8 bb = *(const s16x8*)&WoT[(ct*16 + m)*128 + kt*32 + q*8];
            acc[0][ct] = mfma16(a0, bb, acc[0][ct]);
            acc[1][ct] = mfma16(a1, bb, acc[1][ct]);
        }
    }
    #pragma unroll
    for (int ct = 0; ct < 8; ct++){
        const int col = ct*16 + m;
        const float bov = bo[col];
        #pragma unroll
        for (int rt = 0; rt < 2; rt++){
            #pragma unroll
            for (int i = 0; i < 4; i++){
                const int rl = rw + rt*16 + q*4 + i;
                const float gv = bf2f(Gb[((size_t)b*WH_ + gr0 + rl)*C_ + col]);
                const float sg = 1.f / (1.f + __expf(-gv));
                Tr[rl*130 + col] = f2bf((acc[rt][ct][i] + bov) * (1.f + sg));
            }
        }
    }
    __syncthreads();
    for (int idx = t; idx < 128*128; idx += 256){
        int c = idx >> 7, wh = idx & 127;
        float v = bf2f(Tr[wh*130 + c]) + feat0[(size_t)(b*C_ + c)*WH_ + gr0 + wh];
        outp[(size_t)(b*C_ + c)*WH_ + gr0 + wh] = v;
    }
}

extern "C" void kernel_launch(void* const* d_in, const int* in_sizes, int n_in,
                              void* d_out, int out_size, void* d_ws, size_t ws_size,
                              hipStream_t stream)
{
    (void)in_sizes; (void)n_in; (void)out_size; (void)ws_size;
    const float* feat0 = (const float*)d_in[0];
    const float* feat1 = (const float*)d_in[1];
    const float* geo   = (const float*)d_in[2];
    const float* Wq = (const float*)d_in[3];  const float* bq = (const float*)d_in[4];
    const float* Wk = (const float*)d_in[5];  const float* bk = (const float*)d_in[6];
    const float* Wv = (const float*)d_in[7];  const float* bv = (const float*)d_in[8];
    const float* Wo = (const float*)d_in[9];  const float* bo = (const float*)d_in[10];
    const float* Wg = (const float*)d_in[11]; const float* bg = (const float*)d_in[12];
    const float* Wgate = (const float*)d_in[13]; const float* bgate = (const float*)d_in[14];
    float* outp = (float*)d_out;
    char* ws = (char*)d_ws;
    size_t off = 0;
    auto alloc = [&](size_t bytes) -> void* {
        void* p = (void*)(ws + off);
        off += (bytes + 255) & ~(size_t)255;
        return p;
    };
    u16* Qb = (u16*)alloc((size_t)B_*WH_*C_*2);         // pq (gated, x log2e)
    u16* Gb = (u16*)alloc((size_t)B_*WH_*C_*2);         // geo proj
    u16* Kb = (u16*)alloc((size_t)B_*N_*C_*2);          // pk [b][n][c]
    u16* Vb = (u16*)alloc((size_t)B_*N_*C_*2);          // pv^T [b][c][n]
    u16* Opart = (u16*)alloc((size_t)72*5*256*128*2);   // flash partials [q][c], 5 slots/q-tile
    float* Lp  = (float*)alloc((size_t)72*5*256*4);     // partial row sums
    u16* Wt = (u16*)alloc((size_t)5*16384*2);           // bf16 transposed weights

    k_prep   <<<dim3(320), dim3(256), 0, stream>>>(Wq, Wk, Wv, Wo, Wg, Wt);
    k_proj_kv<<<dim3(512), dim3(512), 0, stream>>>(feat1, bk, bv, Wt, Kb, Vb);
    k_proj_qg<<<dim3(288), dim3(256), 0, stream>>>(feat0, geo, bq, bg, Wgate, bgate, Wt, Qb, Gb);
    k_flash  <<<dim3(256), dim3(1024), 0, stream>>>(Qb, Kb, Vb, Opart, Lp);
    k_out    <<<dim3(144), dim3(256), 0, stream>>>(Opart, Lp, bo, Wt, Gb, feat0, outp);
}

// Round 8
// 272.550 us; speedup vs baseline: 1.0495x; 1.0495x over previous
//
#include <hip/hip_runtime.h>

#define B_ 8
#define C_ 128
#define WH_ 2304
#define N_ 8192

typedef unsigned short u16;
typedef float f32x4 __attribute__((ext_vector_type(4)));
typedef short s16x8 __attribute__((ext_vector_type(8)));
typedef short s16x4 __attribute__((ext_vector_type(4)));
typedef unsigned int u32x2 __attribute__((ext_vector_type(2)));

typedef const unsigned int __attribute__((address_space(1))) ga_u32;
typedef unsigned int __attribute__((address_space(3))) lds_u32;

#define LOG2E 1.4426950408889634f
#define MOFF  64.0f   // fixed softmax offset in log2 domain (no running max)

__device__ __forceinline__ float bf2f(u16 u){
    union { unsigned int i; float f; } x; x.i = ((unsigned int)u) << 16; return x.f;
}
__device__ __forceinline__ u16 f2bf(float f){
    union { float f; unsigned int i; } x; x.f = f;
    unsigned int r = x.i + 0x7fffu + ((x.i >> 16) & 1u);
    return (u16)(r >> 16);
}
// packed f32x2 -> bf16x2 (RNE), single VALU op
__device__ __forceinline__ unsigned int cvtpk(float a, float b){
    unsigned int r;
    asm("v_cvt_pk_bf16_f32 %0, %1, %2" : "=v"(r) : "v"(a), "v"(b));
    return r;
}
// element index inside a [rows][128] bf16 LDS tile with 16B-block xor swizzle
__device__ __forceinline__ int swz(int row, int col){
    return row*128 + ((((col >> 3) ^ (row & 15)) << 3) | (col & 7));
}
__device__ __forceinline__ f32x4 fzero(){ f32x4 z = {0.f, 0.f, 0.f, 0.f}; return z; }
__device__ __forceinline__ f32x4 fmoff(){ f32x4 z = {-MOFF, -MOFF, -MOFF, -MOFF}; return z; }
__device__ __forceinline__ f32x4 mfma16(s16x8 a, s16x8 b, f32x4 c){
    return __builtin_amdgcn_mfma_f32_16x16x32_bf16(a, b, c, 0, 0, 0);
}
__device__ __forceinline__ void gld16(const void* g, void* l){
    __builtin_amdgcn_global_load_lds((ga_u32*)g, (lds_u32*)l, 16, 0, 0);
}
__device__ __forceinline__ s16x8 ldsf(const u16* p){ return *(const s16x8*)p; }
__device__ __forceinline__ s16x8 cvt8(const float* p){
    s16x8 r;
    #pragma unroll
    for (int j = 0; j < 8; j++) r[j] = (short)f2bf(p[j]);
    return r;
}

// ---------------- K0: weights -> bf16 transposed [out][in] ----------------
__global__ __launch_bounds__(256) void k_prep(
    const float* __restrict__ Wq, const float* __restrict__ Wk,
    const float* __restrict__ Wv, const float* __restrict__ Wo,
    const float* __restrict__ Wg, u16* __restrict__ Wt)
{
    const int gid = blockIdx.x*256 + threadIdx.x;     // 5*16384
    const int mi = gid >> 14, e = gid & 16383;
    const int o = e >> 7, i = e & 127;
    const float* src = (mi==0)?Wq:(mi==1)?Wk:(mi==2)?Wv:(mi==3)?Wo:Wg;
    Wt[mi*16384 + o*128 + i] = f2bf(src[i*128 + o]);
}

// ---------------- K1 merged, barrier-free: 0..1023 pk/pv (64 n-rows);
//                  1024..1311 pq/geo+gate (64 q-rows) -------------------------
// A-fragments loaded DIRECTLY from global: feat[c][n]-major means lane-consecutive
// n rows = coalesced f32 loads; the MFMA A layout (lane=row, regs=c-slice) needs
// no transpose staging. Weights as B-fragments from global (L1/L2-resident).
// LDS (16 KB) only for the coalescing round-trip of K / Q / G outputs,
// wave-private 16-row slabs -> zero barriers in the whole kernel.
__device__ __forceinline__ void proj_kv_body(
    u16* SB, int blk,
    const float* __restrict__ feat1,
    const float* __restrict__ bk, const float* __restrict__ bv,
    const u16* __restrict__ Wt,
    u16* __restrict__ Kb, u16* __restrict__ Vb)
{
    const int t = threadIdx.x;
    const int b = blk >> 7;
    const int n0 = (blk & 127) * 64;
    const int lane = t & 63, w = t >> 6, qq = lane >> 4, m = lane & 15;
    const int nr = n0 + w*16 + m;                   // this lane's n row
    s16x8 aA[4];
    #pragma unroll
    for (int kt = 0; kt < 4; kt++){
        #pragma unroll
        for (int j = 0; j < 8; j++)
            aA[kt][j] = (short)f2bf(feat1[((size_t)b*C_ + kt*32 + qq*8 + j)*N_ + nr]);
    }
    const u16* WkT = Wt + 16384;
    const u16* WvT = Wt + 32768;
    f32x4 acc[8];
    // ---- K GEMM ----
    #pragma unroll
    for (int ct = 0; ct < 8; ct++) acc[ct] = fzero();
    #pragma unroll
    for (int kt = 0; kt < 4; kt++){
        #pragma unroll
        for (int ct = 0; ct < 8; ct++){
            const s16x8 bf = *(const s16x8*)&WkT[(ct*16 + m)*128 + kt*32 + qq*8];
            acc[ct] = mfma16(aA[kt], bf, acc[ct]);
        }
    }
    // wave-private Ko staging (rows w*16..w*16+15), coalesced readback
    #pragma unroll
    for (int ct = 0; ct < 8; ct++){
        const int col = ct*16 + m;
        const float bkv = bk[col];
        #pragma unroll
        for (int i = 0; i < 4; i++)
            SB[swz(w*16 + qq*4 + i, col)] = f2bf(acc[ct][i] + bkv);
    }
    #pragma unroll
    for (int j = 0; j < 4; j++){
        const int chunk = j*64 + lane;
        const int row = w*16 + (chunk >> 4);
        const int cb = chunk & 15;
        s16x8 v = ldsf(&SB[row*128 + ((cb ^ (row & 15)) << 3)]);
        *(s16x8*)&Kb[((size_t)b*N_ + n0 + row)*C_ + cb*8] = v;
    }
    // ---- V GEMM (reuse aA/acc) ----
    #pragma unroll
    for (int ct = 0; ct < 8; ct++) acc[ct] = fzero();
    #pragma unroll
    for (int kt = 0; kt < 4; kt++){
        #pragma unroll
        for (int ct = 0; ct < 8; ct++){
            const s16x8 bf = *(const s16x8*)&WvT[(ct*16 + m)*128 + kt*32 + qq*8];
            acc[ct] = mfma16(aA[kt], bf, acc[ct]);
        }
    }
    // direct V^T store: lane holds n = n0 + w*16 + qq*4 + 0..3 of channel col
    #pragma unroll
    for (int ct = 0; ct < 8; ct++){
        const int col = ct*16 + m;
        const float bvv = bv[col];
        u32x2 pk;
        pk.x = cvtpk(acc[ct][0] + bvv, acc[ct][1] + bvv);
        pk.y = cvtpk(acc[ct][2] + bvv, acc[ct][3] + bvv);
        *(u32x2*)&Vb[((size_t)b*C_ + col)*N_ + n0 + w*16 + qq*4] = pk;
    }
}

__device__ __forceinline__ void proj_qg_body(
    u16* SB, int blk,
    const float* __restrict__ feat0, const float* __restrict__ geo,
    const float* __restrict__ bq, const float* __restrict__ bg,
    const float* __restrict__ Wgate, const float* __restrict__ bgate,
    const u16* __restrict__ Wt,
    u16* __restrict__ Qb, u16* __restrict__ Gb)
{
    const int t = threadIdx.x;
    const int b = blk / 36;
    const int r0 = (blk % 36) * 64;
    const int lane = t & 63, w = t >> 6, qq = lane >> 4, m = lane & 15;
    const int ar = w*16 + m;
    s16x8 aQ[4], aG[4];
    #pragma unroll
    for (int kt = 0; kt < 4; kt++){
        #pragma unroll
        for (int j = 0; j < 8; j++)
            aQ[kt][j] = (short)f2bf(feat0[((size_t)b*C_ + kt*32 + qq*8 + j)*WH_ + r0 + ar]);
        aG[kt] = cvt8(&geo[((size_t)b*WH_ + r0 + ar)*C_ + kt*32 + qq*8]);
    }
    f32x4 accq[8], accg[8];
    #pragma unroll
    for (int ct = 0; ct < 8; ct++){ accq[ct] = fzero(); accg[ct] = fzero(); }
    #pragma unroll
    for (int kt = 0; kt < 4; kt++){
        #pragma unroll
        for (int ct = 0; ct < 8; ct++){
            const int bn = ct*16 + m;
            const s16x8 b1 = *(const s16x8*)&Wt[bn*128 + kt*32 + qq*8];
            const s16x8 b2 = *(const s16x8*)&Wt[65536 + bn*128 + kt*32 + qq*8];
            accq[ct] = mfma16(aQ[kt], b1, accq[ct]);
            accg[ct] = mfma16(aG[kt], b2, accg[ct]);
        }
    }
    // fold biases in place (frees registers before the gate phase)
    #pragma unroll
    for (int ct = 0; ct < 8; ct++){
        const int col = ct*16 + m;
        const float bqv = bq[col], bgv = bg[col];
        #pragma unroll
        for (int i = 0; i < 4; i++){ accq[ct][i] += bqv; accg[ct][i] += bgv; }
    }
    float w1v[8], w2v[8];
    #pragma unroll
    for (int ct = 0; ct < 8; ct++){
        const int col = ct*16 + m;
        w1v[ct] = Wgate[col]; w2v[ct] = Wgate[C_ + col];
    }
    const float bg0 = bgate[0];
    float gate[4];
    #pragma unroll
    for (int i = 0; i < 4; i++){
        float p = 0.f;
        #pragma unroll
        for (int ct = 0; ct < 8; ct++)
            p += accq[ct][i] * w1v[ct] + accg[ct][i] * w2v[ct];
        #pragma unroll
        for (int off = 1; off < 16; off <<= 1) p += __shfl_xor(p, off, 64);
        gate[i] = 1.f / (1.f + __expf(-(p + bg0)));
    }
    // wave-private St staging (rows w*16..w*16+15)
    #pragma unroll
    for (int ct = 0; ct < 8; ct++){
        #pragma unroll
        for (int i = 0; i < 4; i++){
            const float pq = accq[ct][i] + gate[i] * accg[ct][i];
            SB[swz(w*16 + qq*4 + i, ct*16 + m)] = f2bf(pq * LOG2E);
        }
    }
    #pragma unroll
    for (int j = 0; j < 4; j++){
        const int chunk = j*64 + lane;
        const int row = w*16 + (chunk >> 4);
        const int cb = chunk & 15;
        s16x8 v = ldsf(&SB[row*128 + ((cb ^ (row & 15)) << 3)]);
        *(s16x8*)&Qb[((size_t)b*WH_ + r0 + row)*C_ + cb*8] = v;
    }
    #pragma unroll
    for (int ct = 0; ct < 8; ct++){
        #pragma unroll
        for (int i = 0; i < 4; i++)
            SB[swz(w*16 + qq*4 + i, ct*16 + m)] = f2bf(accg[ct][i]);
    }
    #pragma unroll
    for (int j = 0; j < 4; j++){
        const int chunk = j*64 + lane;
        const int row = w*16 + (chunk >> 4);
        const int cb = chunk & 15;
        s16x8 v = ldsf(&SB[row*128 + ((cb ^ (row & 15)) << 3)]);
        *(s16x8*)&Gb[((size_t)b*WH_ + r0 + row)*C_ + cb*8] = v;
    }
}

__global__ __launch_bounds__(256, 3) void k_proj(
    const float* __restrict__ feat1,
    const float* __restrict__ bk, const float* __restrict__ bv,
    const float* __restrict__ feat0, const float* __restrict__ geo,
    const float* __restrict__ bq, const float* __restrict__ bg,
    const float* __restrict__ Wgate, const float* __restrict__ bgate,
    const u16* __restrict__ Wt,
    u16* __restrict__ Kb, u16* __restrict__ Vb,
    u16* __restrict__ Qb, u16* __restrict__ Gb)
{
    __shared__ __attribute__((aligned(16))) u16 SB[64*128];   // 16 KB
    if (blockIdx.x < 1024)
        proj_kv_body(SB, blockIdx.x, feat1, bk, bv, Wt, Kb, Vb);
    else
        proj_qg_body(SB, blockIdx.x - 1024, feat0, geo, bq, bg, Wgate, bgate, Wt, Qb, Gb);
}

// ---------------- K2: flash attention (round-7 proven, unchanged) --------------
__global__ __launch_bounds__(1024, 4) void k_flash(
    const u16* __restrict__ Qb, const u16* __restrict__ Kb, const u16* __restrict__ Vb,
    u16* __restrict__ Opart, float* __restrict__ Lp)
{
    __shared__ __attribute__((aligned(16))) u16 KP0[128*128];   // 32 KB each
    __shared__ __attribute__((aligned(16))) u16 KP1[128*128];
    __shared__ __attribute__((aligned(16))) u16 Vt0[128*128];
    __shared__ __attribute__((aligned(16))) u16 Vt1[128*128];
    const int t = threadIdx.x;
    const int lane = t & 63, w = t >> 6;            // 16 waves
    const int q = lane >> 4, m = lane & 15;         // q = quad
    const int b = blockIdx.x & 7;
    const int s = blockIdx.x >> 3;                  // slot 0..31

    f32x4 o[8];
    f32x4 l_acc;                                    // denominator via ones-MFMA
    s16x8 qf[4];
    s16x8 ones8;
    #pragma unroll
    for (int j = 0; j < 8; j++) ones8[j] = (short)0x3F80;   // bf16 1.0

    auto issue = [&](int k){
        const int u = s*18 + k;
        const int n0 = (u & 63) * 128;              // sequential chunk order
        u16* KPd = (k & 1) ? KP1 : KP0;
        u16* Vtd = (k & 1) ? Vt1 : Vt0;
        #pragma unroll
        for (int j = 0; j < 2; j++){
            const int r = w*8 + j*4 + q;            // LDS row 0..127
            // K global row permuted: pi(r) = [pair|q2|h|i] from r = [pair|h|q2|i]
            const int pr = (r & 96) | ((r & 12) << 1) | ((r & 16) >> 2) | (r & 3);
            gld16(Kb + ((size_t)b*N_ + n0 + pr)*C_ + ((m ^ (r & 15)) << 3), &KPd[(w*8 + j*4)*128]);
            gld16(Vb + ((size_t)b*C_ + r)*N_ + n0 + ((m ^ (r & 15)) << 3), &Vtd[(w*8 + j*4)*128]);
        }
    };
    auto load_q = [&](int qb){
        const size_t qrow0 = (size_t)b*WH_ + qb*256;
        #pragma unroll
        for (int kt = 0; kt < 4; kt++)
            qf[kt] = *(const s16x8*)&Qb[(qrow0 + w*16 + m)*C_ + kt*32 + q*8];
    };
    auto zero_acc = [&](){
        #pragma unroll
        for (int ct = 0; ct < 8; ct++) o[ct] = fzero();
        l_acc = fzero();
    };
    auto flush = [&](int qb){
        const int sf = (qb * 64) / 18;
        const size_t pbase = ((size_t)(b*9 + qb)*5 + (s - sf)) * 256;
        #pragma unroll
        for (int ct = 0; ct < 8; ct++){
            u32x2 pk;
            pk.x = cvtpk(o[ct][0], o[ct][1]);
            pk.y = cvtpk(o[ct][2], o[ct][3]);
            *(u32x2*)&Opart[(pbase + w*16 + m)*128 + ct*16 + q*4] = pk;
        }
        // l_acc[i] identical across i and q (ones-MFMA row sums); one lane set writes
        if (q == 0) Lp[pbase + w*16 + m] = l_acc[0];
    };

    issue(0);
    int cur_qb = (s*18) >> 6;
    load_q(cur_qb);
    zero_acc();

    for (int k = 0; k < 18; k++){
        __syncthreads();                 // drains prefetch(k) (a full compute-phase old) + buffer sync
        if (k < 17) issue(k + 1);        // overlaps with compute below
        const u16* KPc = (k & 1) ? KP1 : KP0;
        const u16* Vtc = (k & 1) ? Vt1 : Vt0;

        // Two half-phases: S^T (C-init = -MOFF) for 4 n-groups -> fused K32 PV.
        #pragma unroll
        for (int h = 0; h < 2; h++){
            s16x4 pexp[4];
            #pragma unroll
            for (int n2 = 0; n2 < 4; n2++){
                const int nt = h*4 + n2;
                f32x4 s0 = fmoff();
                const int bn = nt*16 + m;
                #pragma unroll
                for (int kt = 0; kt < 4; kt++){
                    s16x8 kf = ldsf(&KPc[bn*128 + (((kt*4 + q) ^ (bn & 15)) << 3)]);
                    s0 = mfma16(kf, qf[kt], s0);
                }
                union { u32x2 u; s16x4 v; } pp;
                pp.u.x = cvtpk(exp2f(s0[0]), exp2f(s0[1]));
                pp.u.y = cvtpk(exp2f(s0[2]), exp2f(s0[3]));
                pexp[n2] = pp.v;
            }
            // O^T += V^T·P^T as K=32: A = V^T 8-slice (natural order), B = pexp concat
            const s16x8 p80 = __builtin_shufflevector(pexp[0], pexp[1], 0,1,2,3,4,5,6,7);
            const s16x8 p81 = __builtin_shufflevector(pexp[2], pexp[3], 0,1,2,3,4,5,6,7);
            l_acc = mfma16(ones8, p80, l_acc);      // denominator: sum over 32 n per qrow
            l_acc = mfma16(ones8, p81, l_acc);
            #pragma unroll
            for (int ct = 0; ct < 8; ct++){
                const int cc = ct*16 + m;
                const int pair0 = h*2;
                s16x8 vf0 = ldsf(&Vtc[cc*128 + ((((pair0+0)*4 + q) ^ (cc & 15)) << 3)]);
                s16x8 vf1 = ldsf(&Vtc[cc*128 + ((((pair0+1)*4 + q) ^ (cc & 15)) << 3)]);
                o[ct] = mfma16(vf0, p80, o[ct]);
                o[ct] = mfma16(vf1, p81, o[ct]);
            }
        }
        // q-tile bookkeeping (flush uses registers + global stores only; no LDS hazard)
        const int nqb = (k < 17) ? ((s*18 + k + 1) >> 6) : -1;
        if (nqb != cur_qb){
            flush(cur_qb);
            if (nqb >= 0){ load_q(nqb); zero_acc(); cur_qb = nqb; }
        }
    }
}

// ---------------- K3: combine partials, @Wo+bo, geo-gate, +feat0, transpose ------
// 64-row tiles (288 blocks fill 256 CUs), single 16 KB AO/Tr union buffer
// (Tr reuses AO's swz layout; each wave's Tr rows == its AO fragment rows ->
//  wave-private in-place reuse, no extra barrier).
__global__ __launch_bounds__(256, 4) void k_out(
    const u16* __restrict__ Opart, const float* __restrict__ Lp,
    const float* __restrict__ bo, const u16* __restrict__ Wt,
    const u16* __restrict__ Gb, const float* __restrict__ feat0,
    float* __restrict__ outp)
{
    __shared__ __attribute__((aligned(16))) u16 AO[64*128];    // 16 KB (AO, then Tr)
    const int t = threadIdx.x;
    const int r36 = blockIdx.x % 36;
    const int b = blockIdx.x / 36;
    const int qb = r36 >> 2, quarter = r36 & 3;
    const int gr0 = qb*256 + quarter*64;        // row base within batch
    const int qt2 = b*9 + qb;
    const u16* WoT = Wt + 49152;
    const float rsC = 0.088388347648318447f;    // 1/sqrt(128)
    const int sf = (qb*64) / 18;
    const int sl = (qb*64 + 63) / 18;
    const int cnt = sl - sf + 1;                // 4 or 5
    for (int idx = t; idx < 64*16; idx += 256){
        int r = idx >> 4, cb = idx & 15;
        float num[8];
        #pragma unroll
        for (int j = 0; j < 8; j++) num[j] = 0.f;
        float den = 0.f;
        for (int ss = 0; ss < cnt; ss++){
            const size_t base = ((size_t)qt2*5 + ss)*256 + quarter*64 + r;
            s16x8 v = *(const s16x8*)&Opart[base*128 + cb*8];
            #pragma unroll
            for (int j = 0; j < 8; j++) num[j] += bf2f((u16)v[j]);
            den += Lp[base];
        }
        const float sc = rsC / den;
        s16x8 o8;
        #pragma unroll
        for (int j = 0; j < 8; j++) o8[j] = (short)f2bf(num[j] * sc);
        *(s16x8*)&AO[r*128 + ((cb ^ (r & 15)) << 3)] = o8;
    }
    __syncthreads();
    const int lane = t & 63, w = t >> 6;
    const int q = lane >> 4, m = lane & 15;
    f32x4 acc[8];
    #pragma unroll
    for (int ct = 0; ct < 8; ct++) acc[ct] = fzero();
    #pragma unroll
    for (int kt = 0; kt < 4; kt++){
        const int ar = w*16 + m;
        const s16x8 a0 = ldsf(&AO[ar*128 + (((kt*4 + q) ^ (ar & 15)) << 3)]);
        #pragma unroll
        for (int ct = 0; ct < 8; ct++){
            const s16x8 bb = *(const s16x8*)&WoT[(ct*16 + m)*128 + kt*32 + q*8];
            acc[ct] = mfma16(a0, bb, acc[ct]);
        }
    }
    // Tr reuses AO in-place: wave w writes only rows w*16..w*16+15 (its own slab)
    u16* Tr = AO;
    #pragma unroll
    for (int ct = 0; ct < 8; ct++){
        const int col = ct*16 + m;
        const float bov = bo[col];
        #pragma unroll
        for (int i = 0; i < 4; i++){
            const int rl = w*16 + q*4 + i;
            const float gv = bf2f(Gb[((size_t)b*WH_ + gr0 + rl)*C_ + col]);
            const float sg = 1.f / (1.f + __expf(-gv));
            Tr[swz(rl, col)] = f2bf((acc[ct][i] + bov) * (1.f + sg));
        }
    }
    __syncthreads();
    for (int idx = t; idx < 64*128; idx += 256){
        int c = idx >> 6, wh = idx & 63;
        float v = bf2f(Tr[swz(wh, c)]) + feat0[(size_t)(b*C_ + c)*WH_ + gr0 + wh];
        outp[(size_t)(b*C_ + c)*WH_ + gr0 + wh] = v;
    }
}

extern "C" void kernel_launch(void* const* d_in, const int* in_sizes, int n_in,
                              void* d_out, int out_size, void* d_ws, size_t ws_size,
                              hipStream_t stream)
{
    (void)in_sizes; (void)n_in; (void)out_size; (void)ws_size;
    const float* feat0 = (const float*)d_in[0];
    const float* feat1 = (const float*)d_in[1];
    const float* geo   = (const float*)d_in[2];
    const float* Wq = (const float*)d_in[3];  const float* bq = (const float*)d_in[4];
    const float* Wk = (const float*)d_in[5];  const float* bk = (const float*)d_in[6];
    const float* Wv = (const float*)d_in[7];  const float* bv = (const float*)d_in[8];
    const float* Wo = (const float*)d_in[9];  const float* bo = (const float*)d_in[10];
    const float* Wg = (const float*)d_in[11]; const float* bg = (const float*)d_in[12];
    const float* Wgate = (const float*)d_in[13]; const float* bgate = (const float*)d_in[14];
    float* outp = (float*)d_out;
    char* ws = (char*)d_ws;
    size_t off = 0;
    auto alloc = [&](size_t bytes) -> void* {
        void* p = (void*)(ws + off);
        off += (bytes + 255) & ~(size_t)255;
        return p;
    };
    u16* Qb = (u16*)alloc((size_t)B_*WH_*C_*2);         // pq (gated, x log2e)
    u16* Gb = (u16*)alloc((size_t)B_*WH_*C_*2);         // geo proj
    u16* Kb = (u16*)alloc((size_t)B_*N_*C_*2);          // pk [b][n][c]
    u16* Vb = (u16*)alloc((size_t)B_*N_*C_*2);          // pv^T [b][c][n]
    u16* Opart = (u16*)alloc((size_t)72*5*256*128*2);   // flash partials [q][c], 5 slots/q-tile
    float* Lp  = (float*)alloc((size_t)72*5*256*4);     // partial row sums
    u16* Wt = (u16*)alloc((size_t)5*16384*2);           // bf16 transposed weights

    k_prep <<<dim3(320),  dim3(256),  0, stream>>>(Wq, Wk, Wv, Wo, Wg, Wt);
    k_proj <<<dim3(1312), dim3(256),  0, stream>>>(feat1, bk, bv, feat0, geo, bq, bg,
                                                   Wgate, bgate, Wt, Kb, Vb, Qb, Gb);
    k_flash<<<dim3(256),  dim3(1024), 0, stream>>>(Qb, Kb, Vb, Opart, Lp);
    k_out  <<<dim3(288),  dim3(256),  0, stream>>>(Opart, Lp, bo, Wt, Gb, feat0, outp);
}

// Round 9
// 271.976 us; speedup vs baseline: 1.0518x; 1.0021x over previous
//
#include <hip/hip_runtime.h>

#define B_ 8
#define C_ 128
#define WH_ 2304
#define N_ 8192

typedef unsigned short u16;
typedef float f32x4 __attribute__((ext_vector_type(4)));
typedef short s16x8 __attribute__((ext_vector_type(8)));
typedef short s16x4 __attribute__((ext_vector_type(4)));
typedef unsigned int u32x2 __attribute__((ext_vector_type(2)));

typedef const unsigned int __attribute__((address_space(1))) ga_u32;
typedef unsigned int __attribute__((address_space(3))) lds_u32;

#define LOG2E 1.4426950408889634f
#define MOFF  64.0f   // fixed softmax offset in log2 domain (no running max)

__device__ __forceinline__ float bf2f(u16 u){
    union { unsigned int i; float f; } x; x.i = ((unsigned int)u) << 16; return x.f;
}
__device__ __forceinline__ u16 f2bf(float f){
    union { float f; unsigned int i; } x; x.f = f;
    unsigned int r = x.i + 0x7fffu + ((x.i >> 16) & 1u);
    return (u16)(r >> 16);
}
// packed f32x2 -> bf16x2 (RNE), single VALU op
__device__ __forceinline__ unsigned int cvtpk(float a, float b){
    unsigned int r;
    asm("v_cvt_pk_bf16_f32 %0, %1, %2" : "=v"(r) : "v"(a), "v"(b));
    return r;
}
// element index inside a [rows][128] bf16 LDS tile with 16B-block xor swizzle
__device__ __forceinline__ int swz(int row, int col){
    return row*128 + ((((col >> 3) ^ (row & 15)) << 3) | (col & 7));
}
__device__ __forceinline__ f32x4 fzero(){ f32x4 z = {0.f, 0.f, 0.f, 0.f}; return z; }
__device__ __forceinline__ f32x4 fmoff(){ f32x4 z = {-MOFF, -MOFF, -MOFF, -MOFF}; return z; }
__device__ __forceinline__ f32x4 mfma16(s16x8 a, s16x8 b, f32x4 c){
    return __builtin_amdgcn_mfma_f32_16x16x32_bf16(a, b, c, 0, 0, 0);
}
__device__ __forceinline__ void gld16(const void* g, void* l){
    __builtin_amdgcn_global_load_lds((ga_u32*)g, (lds_u32*)l, 16, 0, 0);
}
__device__ __forceinline__ s16x8 ldsf(const u16* p){ return *(const s16x8*)p; }
__device__ __forceinline__ s16x8 cvt8(const float* p){
    s16x8 r;
    #pragma unroll
    for (int j = 0; j < 8; j++) r[j] = (short)f2bf(p[j]);
    return r;
}

// ---------------- K0: weights -> bf16 transposed [out][in] ----------------
__global__ __launch_bounds__(256) void k_prep(
    const float* __restrict__ Wq, const float* __restrict__ Wk,
    const float* __restrict__ Wv, const float* __restrict__ Wo,
    const float* __restrict__ Wg, u16* __restrict__ Wt)
{
    const int gid = blockIdx.x*256 + threadIdx.x;     // 5*16384
    const int mi = gid >> 14, e = gid & 16383;
    const int o = e >> 7, i = e & 127;
    const float* src = (mi==0)?Wq:(mi==1)?Wk:(mi==2)?Wv:(mi==3)?Wo:Wg;
    Wt[mi*16384 + o*128 + i] = f2bf(src[i*128 + o]);
}

// ---------------- K1 merged, barrier-free (round-8 proven) ---------------------
__device__ __forceinline__ void proj_kv_body(
    u16* SB, int blk,
    const float* __restrict__ feat1,
    const float* __restrict__ bk, const float* __restrict__ bv,
    const u16* __restrict__ Wt,
    u16* __restrict__ Kb, u16* __restrict__ Vb)
{
    const int t = threadIdx.x;
    const int b = blk >> 7;
    const int n0 = (blk & 127) * 64;
    const int lane = t & 63, w = t >> 6, qq = lane >> 4, m = lane & 15;
    const int nr = n0 + w*16 + m;                   // this lane's n row
    s16x8 aA[4];
    #pragma unroll
    for (int kt = 0; kt < 4; kt++){
        #pragma unroll
        for (int j = 0; j < 8; j++)
            aA[kt][j] = (short)f2bf(feat1[((size_t)b*C_ + kt*32 + qq*8 + j)*N_ + nr]);
    }
    const u16* WkT = Wt + 16384;
    const u16* WvT = Wt + 32768;
    f32x4 acc[8];
    // ---- K GEMM ----
    #pragma unroll
    for (int ct = 0; ct < 8; ct++) acc[ct] = fzero();
    #pragma unroll
    for (int kt = 0; kt < 4; kt++){
        #pragma unroll
        for (int ct = 0; ct < 8; ct++){
            const s16x8 bf = *(const s16x8*)&WkT[(ct*16 + m)*128 + kt*32 + qq*8];
            acc[ct] = mfma16(aA[kt], bf, acc[ct]);
        }
    }
    // wave-private Ko staging (rows w*16..w*16+15), coalesced readback
    #pragma unroll
    for (int ct = 0; ct < 8; ct++){
        const int col = ct*16 + m;
        const float bkv = bk[col];
        #pragma unroll
        for (int i = 0; i < 4; i++)
            SB[swz(w*16 + qq*4 + i, col)] = f2bf(acc[ct][i] + bkv);
    }
    #pragma unroll
    for (int j = 0; j < 4; j++){
        const int chunk = j*64 + lane;
        const int row = w*16 + (chunk >> 4);
        const int cb = chunk & 15;
        s16x8 v = ldsf(&SB[row*128 + ((cb ^ (row & 15)) << 3)]);
        *(s16x8*)&Kb[((size_t)b*N_ + n0 + row)*C_ + cb*8] = v;
    }
    // ---- V GEMM (reuse aA/acc) ----
    #pragma unroll
    for (int ct = 0; ct < 8; ct++) acc[ct] = fzero();
    #pragma unroll
    for (int kt = 0; kt < 4; kt++){
        #pragma unroll
        for (int ct = 0; ct < 8; ct++){
            const s16x8 bf = *(const s16x8*)&WvT[(ct*16 + m)*128 + kt*32 + qq*8];
            acc[ct] = mfma16(aA[kt], bf, acc[ct]);
        }
    }
    // direct V^T store: lane holds n = n0 + w*16 + qq*4 + 0..3 of channel col
    #pragma unroll
    for (int ct = 0; ct < 8; ct++){
        const int col = ct*16 + m;
        const float bvv = bv[col];
        u32x2 pk;
        pk.x = cvtpk(acc[ct][0] + bvv, acc[ct][1] + bvv);
        pk.y = cvtpk(acc[ct][2] + bvv, acc[ct][3] + bvv);
        *(u32x2*)&Vb[((size_t)b*C_ + col)*N_ + n0 + w*16 + qq*4] = pk;
    }
}

__device__ __forceinline__ void proj_qg_body(
    u16* SB, int blk,
    const float* __restrict__ feat0, const float* __restrict__ geo,
    const float* __restrict__ bq, const float* __restrict__ bg,
    const float* __restrict__ Wgate, const float* __restrict__ bgate,
    const u16* __restrict__ Wt,
    u16* __restrict__ Qb, u16* __restrict__ Gb)
{
    const int t = threadIdx.x;
    const int b = blk / 36;
    const int r0 = (blk % 36) * 64;
    const int lane = t & 63, w = t >> 6, qq = lane >> 4, m = lane & 15;
    const int ar = w*16 + m;
    s16x8 aQ[4], aG[4];
    #pragma unroll
    for (int kt = 0; kt < 4; kt++){
        #pragma unroll
        for (int j = 0; j < 8; j++)
            aQ[kt][j] = (short)f2bf(feat0[((size_t)b*C_ + kt*32 + qq*8 + j)*WH_ + r0 + ar]);
        aG[kt] = cvt8(&geo[((size_t)b*WH_ + r0 + ar)*C_ + kt*32 + qq*8]);
    }
    f32x4 accq[8], accg[8];
    #pragma unroll
    for (int ct = 0; ct < 8; ct++){ accq[ct] = fzero(); accg[ct] = fzero(); }
    #pragma unroll
    for (int kt = 0; kt < 4; kt++){
        #pragma unroll
        for (int ct = 0; ct < 8; ct++){
            const int bn = ct*16 + m;
            const s16x8 b1 = *(const s16x8*)&Wt[bn*128 + kt*32 + qq*8];
            const s16x8 b2 = *(const s16x8*)&Wt[65536 + bn*128 + kt*32 + qq*8];
            accq[ct] = mfma16(aQ[kt], b1, accq[ct]);
            accg[ct] = mfma16(aG[kt], b2, accg[ct]);
        }
    }
    // fold biases in place (frees registers before the gate phase)
    #pragma unroll
    for (int ct = 0; ct < 8; ct++){
        const int col = ct*16 + m;
        const float bqv = bq[col], bgv = bg[col];
        #pragma unroll
        for (int i = 0; i < 4; i++){ accq[ct][i] += bqv; accg[ct][i] += bgv; }
    }
    float w1v[8], w2v[8];
    #pragma unroll
    for (int ct = 0; ct < 8; ct++){
        const int col = ct*16 + m;
        w1v[ct] = Wgate[col]; w2v[ct] = Wgate[C_ + col];
    }
    const float bg0 = bgate[0];
    float gate[4];
    #pragma unroll
    for (int i = 0; i < 4; i++){
        float p = 0.f;
        #pragma unroll
        for (int ct = 0; ct < 8; ct++)
            p += accq[ct][i] * w1v[ct] + accg[ct][i] * w2v[ct];
        #pragma unroll
        for (int off = 1; off < 16; off <<= 1) p += __shfl_xor(p, off, 64);
        gate[i] = 1.f / (1.f + __expf(-(p + bg0)));
    }
    // wave-private St staging (rows w*16..w*16+15)
    #pragma unroll
    for (int ct = 0; ct < 8; ct++){
        #pragma unroll
        for (int i = 0; i < 4; i++){
            const float pq = accq[ct][i] + gate[i] * accg[ct][i];
            SB[swz(w*16 + qq*4 + i, ct*16 + m)] = f2bf(pq * LOG2E);
        }
    }
    #pragma unroll
    for (int j = 0; j < 4; j++){
        const int chunk = j*64 + lane;
        const int row = w*16 + (chunk >> 4);
        const int cb = chunk & 15;
        s16x8 v = ldsf(&SB[row*128 + ((cb ^ (row & 15)) << 3)]);
        *(s16x8*)&Qb[((size_t)b*WH_ + r0 + row)*C_ + cb*8] = v;
    }
    #pragma unroll
    for (int ct = 0; ct < 8; ct++){
        #pragma unroll
        for (int i = 0; i < 4; i++)
            SB[swz(w*16 + qq*4 + i, ct*16 + m)] = f2bf(accg[ct][i]);
    }
    #pragma unroll
    for (int j = 0; j < 4; j++){
        const int chunk = j*64 + lane;
        const int row = w*16 + (chunk >> 4);
        const int cb = chunk & 15;
        s16x8 v = ldsf(&SB[row*128 + ((cb ^ (row & 15)) << 3)]);
        *(s16x8*)&Gb[((size_t)b*WH_ + r0 + row)*C_ + cb*8] = v;
    }
}

__global__ __launch_bounds__(256, 3) void k_proj(
    const float* __restrict__ feat1,
    const float* __restrict__ bk, const float* __restrict__ bv,
    const float* __restrict__ feat0, const float* __restrict__ geo,
    const float* __restrict__ bq, const float* __restrict__ bg,
    const float* __restrict__ Wgate, const float* __restrict__ bgate,
    const u16* __restrict__ Wt,
    u16* __restrict__ Kb, u16* __restrict__ Vb,
    u16* __restrict__ Qb, u16* __restrict__ Gb)
{
    __shared__ __attribute__((aligned(16))) u16 SB[64*128];   // 16 KB
    if (blockIdx.x < 1024)
        proj_kv_body(SB, blockIdx.x, feat1, bk, bv, Wt, Kb, Vb);
    else
        proj_qg_body(SB, blockIdx.x - 1024, feat0, geo, bq, bg, Wgate, bgate, Wt, Qb, Gb);
}

// ---------------- K2: flash attention, 8 waves x 32 q-rows, chunk=128 ----------
// LDS-read-bound fix: each KP fragment feeds 2 S^T MFMAs (s0,s1) and each V
// fragment feeds 2 PV MFMAs (two q-groups) -> LDS reads per unit work halved
// (64 b128/wave-step serving 32 q-rows). (512,2): regs <= 256, no spills.
__global__ __launch_bounds__(512, 2) void k_flash(
    const u16* __restrict__ Qb, const u16* __restrict__ Kb, const u16* __restrict__ Vb,
    u16* __restrict__ Opart, float* __restrict__ Lp)
{
    __shared__ __attribute__((aligned(16))) u16 KP0[128*128];   // 32 KB each
    __shared__ __attribute__((aligned(16))) u16 KP1[128*128];
    __shared__ __attribute__((aligned(16))) u16 Vt0[128*128];
    __shared__ __attribute__((aligned(16))) u16 Vt1[128*128];
    const int t = threadIdx.x;
    const int lane = t & 63, w = t >> 6;            // 8 waves
    const int q = lane >> 4, m = lane & 15;         // q = quad
    const int rw = w * 32;
    const int b = blockIdx.x & 7;
    const int s = blockIdx.x >> 3;                  // slot 0..31

    f32x4 o[2][8];
    f32x4 l_acc[2];
    s16x8 qf[2][4];
    s16x8 ones8;
    #pragma unroll
    for (int j = 0; j < 8; j++) ones8[j] = (short)0x3F80;   // bf16 1.0

    auto issue = [&](int k){
        const int u = s*18 + k;
        const int n0 = (u & 63) * 128;              // sequential chunk order
        u16* KPd = (k & 1) ? KP1 : KP0;
        u16* Vtd = (k & 1) ? Vt1 : Vt0;
        #pragma unroll
        for (int j = 0; j < 4; j++){
            const int r = w*16 + j*4 + q;           // LDS row 0..127
            // K global row permuted: pi(r) = [pair|q2|h|i] from r = [pair|h|q2|i]
            const int pr = (r & 96) | ((r & 12) << 1) | ((r & 16) >> 2) | (r & 3);
            gld16(Kb + ((size_t)b*N_ + n0 + pr)*C_ + ((m ^ (r & 15)) << 3), &KPd[(w*16 + j*4)*128]);
            gld16(Vb + ((size_t)b*C_ + r)*N_ + n0 + ((m ^ (r & 15)) << 3), &Vtd[(w*16 + j*4)*128]);
        }
    };
    auto load_q = [&](int qb){
        const size_t qrow0 = (size_t)b*WH_ + qb*256;
        #pragma unroll
        for (int rt = 0; rt < 2; rt++){
            #pragma unroll
            for (int kt = 0; kt < 4; kt++)
                qf[rt][kt] = *(const s16x8*)&Qb[(qrow0 + rw + rt*16 + m)*C_ + kt*32 + q*8];
        }
    };
    auto zero_acc = [&](){
        #pragma unroll
        for (int ct = 0; ct < 8; ct++){ o[0][ct] = fzero(); o[1][ct] = fzero(); }
        l_acc[0] = fzero(); l_acc[1] = fzero();
    };
    auto flush = [&](int qb){
        const int sf = (qb * 64) / 18;
        const size_t pbase = ((size_t)(b*9 + qb)*5 + (s - sf)) * 256;
        #pragma unroll
        for (int ct = 0; ct < 8; ct++){
            #pragma unroll
            for (int rt = 0; rt < 2; rt++){
                u32x2 pk;
                pk.x = cvtpk(o[rt][ct][0], o[rt][ct][1]);
                pk.y = cvtpk(o[rt][ct][2], o[rt][ct][3]);
                *(u32x2*)&Opart[(pbase + rw + rt*16 + m)*128 + ct*16 + q*4] = pk;
            }
        }
        // l_acc[rt][i] identical across i and q (ones-MFMA row sums)
        if (q == 0){
            Lp[pbase + rw + m] = l_acc[0][0];
            Lp[pbase + rw + 16 + m] = l_acc[1][0];
        }
    };

    issue(0);
    int cur_qb = (s*18) >> 6;
    load_q(cur_qb);
    zero_acc();

    for (int k = 0; k < 18; k++){
        __syncthreads();                 // drains prefetch(k) (a full compute-phase old) + buffer sync
        if (k < 17) issue(k + 1);        // overlaps with compute below
        const u16* KPc = (k & 1) ? KP1 : KP0;
        const u16* Vtc = (k & 1) ? Vt1 : Vt0;

        // Two half-phases: S^T (C-init = -MOFF) for 4 n-groups x 2 q-groups,
        // then fused K32 PV; every LDS fragment feeds 2 MFMAs.
        #pragma unroll
        for (int h = 0; h < 2; h++){
            s16x4 pexp[4][2];
            #pragma unroll
            for (int n2 = 0; n2 < 4; n2++){
                const int nt = h*4 + n2;
                f32x4 s0 = fmoff(), s1 = fmoff();
                const int bn = nt*16 + m;
                #pragma unroll
                for (int kt = 0; kt < 4; kt++){
                    s16x8 kf = ldsf(&KPc[bn*128 + (((kt*4 + q) ^ (bn & 15)) << 3)]);
                    s0 = mfma16(kf, qf[0][kt], s0);
                    s1 = mfma16(kf, qf[1][kt], s1);
                }
                union { u32x2 u; s16x4 v; } p0, p1;
                p0.u.x = cvtpk(exp2f(s0[0]), exp2f(s0[1]));
                p0.u.y = cvtpk(exp2f(s0[2]), exp2f(s0[3]));
                p1.u.x = cvtpk(exp2f(s1[0]), exp2f(s1[1]));
                p1.u.y = cvtpk(exp2f(s1[2]), exp2f(s1[3]));
                pexp[n2][0] = p0.v; pexp[n2][1] = p1.v;
            }
            // K32 B-operands per q-group: pA (n-slice 0) pairs with vf0, pB with vf1
            const s16x8 pA0 = __builtin_shufflevector(pexp[0][0], pexp[1][0], 0,1,2,3,4,5,6,7);
            const s16x8 pB0 = __builtin_shufflevector(pexp[2][0], pexp[3][0], 0,1,2,3,4,5,6,7);
            const s16x8 pA1 = __builtin_shufflevector(pexp[0][1], pexp[1][1], 0,1,2,3,4,5,6,7);
            const s16x8 pB1 = __builtin_shufflevector(pexp[2][1], pexp[3][1], 0,1,2,3,4,5,6,7);
            l_acc[0] = mfma16(ones8, pA0, l_acc[0]);
            l_acc[0] = mfma16(ones8, pB0, l_acc[0]);
            l_acc[1] = mfma16(ones8, pA1, l_acc[1]);
            l_acc[1] = mfma16(ones8, pB1, l_acc[1]);
            #pragma unroll
            for (int ct = 0; ct < 8; ct++){
                const int cc = ct*16 + m;
                const int pair0 = h*2;
                s16x8 vf0 = ldsf(&Vtc[cc*128 + ((((pair0+0)*4 + q) ^ (cc & 15)) << 3)]);
                s16x8 vf1 = ldsf(&Vtc[cc*128 + ((((pair0+1)*4 + q) ^ (cc & 15)) << 3)]);
                o[0][ct] = mfma16(vf0, pA0, o[0][ct]);
                o[0][ct] = mfma16(vf1, pB0, o[0][ct]);
                o[1][ct] = mfma16(vf0, pA1, o[1][ct]);
                o[1][ct] = mfma16(vf1, pB1, o[1][ct]);
            }
        }
        // q-tile bookkeeping (flush uses registers + global stores only; no LDS hazard)
        const int nqb = (k < 17) ? ((s*18 + k + 1) >> 6) : -1;
        if (nqb != cur_qb){
            flush(cur_qb);
            if (nqb >= 0){ load_q(nqb); zero_acc(); cur_qb = nqb; }
        }
    }
}

// ---------------- K3: combine partials, @Wo+bo, geo-gate, +feat0 (round-8) -----
__global__ __launch_bounds__(256, 4) void k_out(
    const u16* __restrict__ Opart, const float* __restrict__ Lp,
    const float* __restrict__ bo, const u16* __restrict__ Wt,
    const u16* __restrict__ Gb, const float* __restrict__ feat0,
    float* __restrict__ outp)
{
    __shared__ __attribute__((aligned(16))) u16 AO[64*128];    // 16 KB (AO, then Tr)
    const int t = threadIdx.x;
    const int r36 = blockIdx.x % 36;
    const int b = blockIdx.x / 36;
    const int qb = r36 >> 2, quarter = r36 & 3;
    const int gr0 = qb*256 + quarter*64;        // row base within batch
    const int qt2 = b*9 + qb;
    const u16* WoT = Wt + 49152;
    const float rsC = 0.088388347648318447f;    // 1/sqrt(128)
    const int sf = (qb*64) / 18;
    const int sl = (qb*64 + 63) / 18;
    const int cnt = sl - sf + 1;                // 4 or 5
    for (int idx = t; idx < 64*16; idx += 256){
        int r = idx >> 4, cb = idx & 15;
        float num[8];
        #pragma unroll
        for (int j = 0; j < 8; j++) num[j] = 0.f;
        float den = 0.f;
        for (int ss = 0; ss < cnt; ss++){
            const size_t base = ((size_t)qt2*5 + ss)*256 + quarter*64 + r;
            s16x8 v = *(const s16x8*)&Opart[base*128 + cb*8];
            #pragma unroll
            for (int j = 0; j < 8; j++) num[j] += bf2f((u16)v[j]);
            den += Lp[base];
        }
        const float sc = rsC / den;
        s16x8 o8;
        #pragma unroll
        for (int j = 0; j < 8; j++) o8[j] = (short)f2bf(num[j] * sc);
        *(s16x8*)&AO[r*128 + ((cb ^ (r & 15)) << 3)] = o8;
    }
    __syncthreads();
    const int lane = t & 63, w = t >> 6;
    const int q = lane >> 4, m = lane & 15;
    f32x4 acc[8];
    #pragma unroll
    for (int ct = 0; ct < 8; ct++) acc[ct] = fzero();
    #pragma unroll
    for (int kt = 0; kt < 4; kt++){
        const int ar = w*16 + m;
        const s16x8 a0 = ldsf(&AO[ar*128 + (((kt*4 + q) ^ (ar & 15)) << 3)]);
        #pragma unroll
        for (int ct = 0; ct < 8; ct++){
            const s16x8 bb = *(const s16x8*)&WoT[(ct*16 + m)*128 + kt*32 + q*8];
            acc[ct] = mfma16(a0, bb, acc[ct]);
        }
    }
    // Tr reuses AO in-place: wave w writes only rows w*16..w*16+15 (its own slab)
    u16* Tr = AO;
    #pragma unroll
    for (int ct = 0; ct < 8; ct++){
        const int col = ct*16 + m;
        const float bov = bo[col];
        #pragma unroll
        for (int i = 0; i < 4; i++){
            const int rl = w*16 + q*4 + i;
            const float gv = bf2f(Gb[((size_t)b*WH_ + gr0 + rl)*C_ + col]);
            const float sg = 1.f / (1.f + __expf(-gv));
            Tr[swz(rl, col)] = f2bf((acc[ct][i] + bov) * (1.f + sg));
        }
    }
    __syncthreads();
    for (int idx = t; idx < 64*128; idx += 256){
        int c = idx >> 6, wh = idx & 63;
        float v = bf2f(Tr[swz(wh, c)]) + feat0[(size_t)(b*C_ + c)*WH_ + gr0 + wh];
        outp[(size_t)(b*C_ + c)*WH_ + gr0 + wh] = v;
    }
}

extern "C" void kernel_launch(void* const* d_in, const int* in_sizes, int n_in,
                              void* d_out, int out_size, void* d_ws, size_t ws_size,
                              hipStream_t stream)
{
    (void)in_sizes; (void)n_in; (void)out_size; (void)ws_size;
    const float* feat0 = (const float*)d_in[0];
    const float* feat1 = (const float*)d_in[1];
    const float* geo   = (const float*)d_in[2];
    const float* Wq = (const float*)d_in[3];  const float* bq = (const float*)d_in[4];
    const float* Wk = (const float*)d_in[5];  const float* bk = (const float*)d_in[6];
    const float* Wv = (const float*)d_in[7];  const float* bv = (const float*)d_in[8];
    const float* Wo = (const float*)d_in[9];  const float* bo = (const float*)d_in[10];
    const float* Wg = (const float*)d_in[11]; const float* bg = (const float*)d_in[12];
    const float* Wgate = (const float*)d_in[13]; const float* bgate = (const float*)d_in[14];
    float* outp = (float*)d_out;
    char* ws = (char*)d_ws;
    size_t off = 0;
    auto alloc = [&](size_t bytes) -> void* {
        void* p = (void*)(ws + off);
        off += (bytes + 255) & ~(size_t)255;
        return p;
    };
    u16* Qb = (u16*)alloc((size_t)B_*WH_*C_*2);         // pq (gated, x log2e)
    u16* Gb = (u16*)alloc((size_t)B_*WH_*C_*2);         // geo proj
    u16* Kb = (u16*)alloc((size_t)B_*N_*C_*2);          // pk [b][n][c]
    u16* Vb = (u16*)alloc((size_t)B_*N_*C_*2);          // pv^T [b][c][n]
    u16* Opart = (u16*)alloc((size_t)72*5*256*128*2);   // flash partials [q][c], 5 slots/q-tile
    float* Lp  = (float*)alloc((size_t)72*5*256*4);     // partial row sums
    u16* Wt = (u16*)alloc((size_t)5*16384*2);           // bf16 transposed weights

    k_prep <<<dim3(320),  dim3(256), 0, stream>>>(Wq, Wk, Wv, Wo, Wg, Wt);
    k_proj <<<dim3(1312), dim3(256), 0, stream>>>(feat1, bk, bv, feat0, geo, bq, bg,
                                                  Wgate, bgate, Wt, Kb, Vb, Qb, Gb);
    k_flash<<<dim3(256),  dim3(512), 0, stream>>>(Qb, Kb, Vb, Opart, Lp);
    k_out  <<<dim3(288),  dim3(256), 0, stream>>>(Opart, Lp, bo, Wt, Gb, feat0, outp);
}